// Round 13
// baseline (413.605 us; speedup 1.0000x reference)
//
#include <hip/hip_runtime.h>
#include <math.h>

#define NN 100000
#define TT 512
#define EE 1024
#define NSTEP (TT - 1)              // 511
#define NE (NSTEP * EE)             // 523,264 edges
#define NCHUNK (NE / 256)           // 2044 chunks of 256 edges (chunk ⊂ one step)
#define FLOWG_FULL NCHUNK           // 2044: one chunk per block, all co-resident
#define FLOWG_HALF 512              // proven fallback config (4 chunks/block)
#define WINDOW 256                  // chunks of probe-ahead (64 steps)
#define MU 0.05f
#define RHO 32.0f
#define CAP (NE * 2)                // 1,046,528 max list entries
#define NOTREADY 0xFFFFFFFFu        // X values finite positive: never this bit pattern
#define SCAN_BLK 1024
#define SCAN_NB ((NN + SCAN_BLK - 1) / SCAN_BLK)   // 98
#define RB 32                       // rows per fill tile
#define NRC (TT / RB)               // 16 row chunks
#define FILL_BX ((NN / 4 + 255) / 256)             // 98 blocks in node dim

#define AGT __HIP_MEMORY_SCOPE_AGENT
#define WGS __HIP_MEMORY_SCOPE_WORKGROUP
#define RLX __ATOMIC_RELAXED

typedef float f32x4 __attribute__((ext_vector_type(4)));

__device__ __forceinline__ float sigmoid_f(float x) {
    return 1.0f / (1.0f + expf(-x));
}

__device__ __forceinline__ unsigned try_val(const unsigned* pub, int p) {
    return __hip_atomic_load((unsigned*)&pub[p], RLX, AGT);
}
__device__ __forceinline__ void publish(unsigned* pub, int p, float v) {
    __hip_atomic_store(&pub[p], __float_as_uint(v), RLX, AGT);
}

__device__ __forceinline__ int lower_bound(const unsigned* __restrict__ a,
                                           int lo, int hi, unsigned key) {
    while (lo < hi) {
        int mid = (lo + hi) >> 1;
        if (a[mid] < key) lo = mid + 1; else hi = mid;
    }
    return lo;
}

// Phase 0: X0 = sigmoid(logit) + row 0 + zero cnt/cur (i < NN), reset pub
// slots (i < NE), reset the chunk-progress counter. Launched over NE range.
__global__ void k_init(const float* __restrict__ logit, float* __restrict__ X0f,
                       float* __restrict__ out, int* __restrict__ cnt,
                       int* __restrict__ cur, unsigned* __restrict__ pub,
                       int* __restrict__ done) {
    int i = blockIdx.x * blockDim.x + threadIdx.x;
    if (i < NE) {
        pub[2 * i]     = NOTREADY;
        pub[2 * i + 1] = NOTREADY;
        if (i == 0) *done = 0;
        if (i < NN) {
            float x = sigmoid_f(logit[i]);
            X0f[i] = x;
            out[i] = x;          // row 0 of X output
            cnt[i] = 0;
            cur[i] = 0;
        }
    }
}

// Phase 0b: count per-node list entries (only s==1 edges modify state).
__global__ void k_count(const int* __restrict__ edges, int* __restrict__ cnt) {
    int i = blockIdx.x * blockDim.x + threadIdx.x;
    if (i < NE) {
        int s = edges[3 * i + 2];
        if (s) {
            atomicAdd(&cnt[edges[3 * i + 0]], 1);
            atomicAdd(&cnt[edges[3 * i + 1]], 1);
        }
    }
}

// Phase 0c-A: per-block (1024 elems, 256 thr x int4) reduce -> bsum[b].
__global__ void __launch_bounds__(256) k_scanA(const int* __restrict__ cnt,
                                               int* __restrict__ bsum) {
    __shared__ int sh[256];
    const int t = threadIdx.x;
    const int base = blockIdx.x * SCAN_BLK + t * 4;
    int s = 0;
    if (base + 3 < NN) {
        const int4 v = *(const int4*)(cnt + base);
        s = v.x + v.y + v.z + v.w;
    } else {
        for (int k = 0; k < 4; ++k) if (base + k < NN) s += cnt[base + k];
    }
    sh[t] = s;
    __syncthreads();
    for (int o = 128; o > 0; o >>= 1) {
        if (t < o) sh[t] += sh[t + o];
        __syncthreads();
    }
    if (t == 0) bsum[blockIdx.x] = sh[0];
}

// Phase 0c-C: per-block local exclusive scan + block offset (each block
// redundantly scans the 98 block sums in LDS -> no separate scanB launch).
__global__ void __launch_bounds__(256) k_scanC(const int* __restrict__ cnt,
                                               const int* __restrict__ bsum,
                                               int* __restrict__ off) {
    __shared__ int sh[256];
    __shared__ int sb[128];
    const int t = threadIdx.x;

    if (t < 128) sb[t] = (t < SCAN_NB) ? bsum[t] : 0;
    __syncthreads();
    for (int o = 1; o < 128; o <<= 1) {
        int x = (t < 128 && t >= o) ? sb[t - o] : 0;
        __syncthreads();
        if (t < 128) sb[t] += x;            // inclusive scan of block sums
        __syncthreads();
    }
    const int boff = (blockIdx.x == 0) ? 0 : sb[blockIdx.x - 1];

    const int base = blockIdx.x * SCAN_BLK + t * 4;
    int a0 = 0, a1 = 0, a2 = 0, a3 = 0;
    if (base + 3 < NN) {
        const int4 v = *(const int4*)(cnt + base);
        a0 = v.x; a1 = v.y; a2 = v.z; a3 = v.w;
    } else {
        if (base + 0 < NN) a0 = cnt[base + 0];
        if (base + 1 < NN) a1 = cnt[base + 1];
        if (base + 2 < NN) a2 = cnt[base + 2];
    }
    const int s = a0 + a1 + a2 + a3;
    sh[t] = s;
    __syncthreads();
    for (int o = 1; o < 256; o <<= 1) {
        int x = (t >= o) ? sh[t - o] : 0;
        __syncthreads();
        sh[t] += x;
        __syncthreads();
    }
    int ex = sh[t] - s + boff;
    if (base + 3 < NN) {
        int4 w; w.x = ex; w.y = ex + a0; w.z = ex + a0 + a1; w.w = ex + a0 + a1 + a2;
        *(int4*)(off + base) = w;
    } else {
        if (base + 0 < NN) off[base + 0] = ex;
        if (base + 1 < NN) off[base + 1] = ex + a0;
        if (base + 2 < NN) off[base + 2] = ex + a0 + a1;
    }
}

// Phase 0d: place packed keys (t*EE+e)<<1 | side into per-node unordered lists.
__global__ void k_place(const int* __restrict__ edges,
                        const int* __restrict__ off, int* __restrict__ cur,
                        unsigned* __restrict__ ent) {
    int i = blockIdx.x * blockDim.x + threadIdx.x;
    if (i < NE) {
        int s = edges[3 * i + 2];
        if (s) {
            int u = edges[3 * i + 0];
            int v = edges[3 * i + 1];
            unsigned key = ((unsigned)i) << 1;
            ent[off[u] + atomicAdd(&cur[u], 1)] = key;        // side 0: -md
            ent[off[v] + atomicAdd(&cur[v], 1)] = key | 1u;   // side 1: +md
        }
    }
}

// Phase 0e: sort each node's list (keys unique -> deterministic). c ~ 5 avg.
__global__ void k_sort(const int* __restrict__ off, const int* __restrict__ cur,
                       unsigned* __restrict__ ent) {
    int n = blockIdx.x * blockDim.x + threadIdx.x;
    if (n >= NN) return;
    int lo = off[n], c = cur[n];
    for (int k = 1; k < c; ++k) {
        unsigned key = ent[lo + k];
        int j = k;
        while (j > 0 && ent[lo + j - 1] > key) {
            ent[lo + j] = ent[lo + j - 1];
            --j;
        }
        ent[lo + j] = key;
    }
}

// Phase 1: dataflow evaluation, one thread per edge, one chunk per block,
// with FRONTIER GATING: before probing, a block sleeps until the completed-
// chunk counter is within WINDOW of its chunk (lane 0 polls -> 1 line, long
// sleeps). This kills R12's probe storm (177 MB fetch) while keeping every
// chunk's block resident (no serial-round depth multiplier). Progress proof:
// chunks <= WINDOW never gate; when all chunks < c are done, done >= c.
__global__ void __launch_bounds__(256, 8)
k_flow(const int* __restrict__ edges, const float* __restrict__ theta,
       const float* __restrict__ X0f, const int* __restrict__ off,
       const int* __restrict__ cur, const unsigned* __restrict__ ent,
       unsigned* __restrict__ pub, float* __restrict__ out_kappa,
       int* __restrict__ done) {
    const float eps = sigmoid_f(theta[0]);
    for (int c = blockIdx.x; c < NCHUNK; c += gridDim.x) {
        if (c > WINDOW) {                       // frontier gate
            if (threadIdx.x == 0) {
                while (__hip_atomic_load(done, RLX, AGT) + WINDOW < c)
                    __builtin_amdgcn_s_sleep(64);
            }
            __syncthreads();
        }

        const int i = (c << 8) + threadIdx.x;
        const int t = i >> 10;                     // i / EE
        const int u = edges[3 * i + 0];
        const int v = edges[3 * i + 1];
        const int s = edges[3 * i + 2];

        const unsigned stepkey = ((unsigned)t) << 11;

        const int lu = off[u], hu = lu + cur[u];
        const int qu = lower_bound(ent, lu, hu, stepkey);
        const int lv = off[v], hv = lv + cur[v];
        const int qv = lower_bound(ent, lv, hv, stepkey);

        int mu_ = -1, mv_ = -1;
        if (s) {
            const unsigned ku = ((unsigned)i) << 1;
            mu_ = qu; while (ent[mu_] != ku) ++mu_;
            const unsigned kv = ku | 1u;
            mv_ = qv; while (ent[mv_] != kv) ++mv_;
        }

        bool have_xu = (qu == lu);
        bool have_xv = (qv == lv);
        float xu = have_xu ? X0f[u] : 0.0f;
        float xv = have_xv ? X0f[v] : 0.0f;
        bool m_rdy = false;
        bool pu_done = (s == 0);
        bool pv_done = (s == 0);
        float m = 0.0f, diff = 0.0f;
        int tries = 0;

        while (!(m_rdy && pu_done && pv_done)) {
            if (!have_xu) {
                unsigned w = try_val(pub, qu - 1);
                if (w != NOTREADY) { xu = __uint_as_float(w); have_xu = true; }
            }
            if (!have_xv) {
                unsigned w = try_val(pub, qv - 1);
                if (w != NOTREADY) { xv = __uint_as_float(w); have_xv = true; }
            }
            if (have_xu && have_xv && !m_rdy) {
                diff = xu - xv;
                m = MU * diff;
                m_rdy = true;
            }
            if (m_rdy && !pu_done) {
                if (mu_ == qu) { publish(pub, mu_, xu - m); pu_done = true; }
                else {
                    unsigned w = try_val(pub, mu_ - 1);
                    if (w != NOTREADY) {
                        publish(pub, mu_, __uint_as_float(w) - m);
                        pu_done = true;
                    }
                }
            }
            if (m_rdy && !pv_done) {
                if (mv_ == qv) { publish(pub, mv_, xv + m); pv_done = true; }
                else {
                    unsigned w = try_val(pub, mv_ - 1);
                    if (w != NOTREADY) {
                        publish(pub, mv_, __uint_as_float(w) + m);
                        pv_done = true;
                    }
                }
            }
            if (!(m_rdy && pu_done && pv_done)) {
                ++tries;
                if (tries > 24)     __builtin_amdgcn_s_sleep(4);
                else if (tries > 6) __builtin_amdgcn_s_sleep(2);
            }
        }
        __builtin_nontemporal_store(sigmoid_f(RHO * (eps - fabsf(diff))),
                                    &out_kappa[i]);

        __syncthreads();                        // all publishes of chunk done
        if (threadIdx.x == 0) atomicAdd(done, 1);
    }
}

// Phase 2: reconstruct X rows from published running values. Separate launch
// => kernel-boundary coherence => plain cached pub reads. Non-temporal
// float4 stores: out is a write-only 204 MB stream, keep it out of L2.
__global__ void __launch_bounds__(256) k_fill_pub(float* __restrict__ out,
                                                  const float* __restrict__ X0f,
                                                  const int* __restrict__ off,
                                                  const int* __restrict__ cur,
                                                  const unsigned* __restrict__ ent,
                                                  const unsigned* __restrict__ pub) {
    const int n0 = (blockIdx.x * 256 + threadIdx.x) * 4;
    if (n0 >= NN) return;                  // NN % 4 == 0: full float4 valid
    const int r0 = blockIdx.y * RB;
    const unsigned key0 = ((unsigned)r0) << 11;

    int   p[4], e2[4];
    unsigned nxt[4];
    float val[4];
    #pragma unroll
    for (int j = 0; j < 4; ++j) {
        const int n = n0 + j;
        const int lo = off[n];
        e2[j] = lo + cur[n];
        int q = lower_bound(ent, lo, e2[j], key0);
        val[j] = (q > lo) ? __uint_as_float(pub[q - 1]) : X0f[n];
        p[j] = q;
        nxt[j] = (q < e2[j]) ? ent[q] : 0xFFFFFFFFu;
    }

    const int rstart = (r0 == 0) ? 1 : r0;   // row 0 written by k_init
    for (int r = rstart; r < r0 + RB; ++r) {
        const unsigned lim = ((unsigned)r) << 11;   // keys with t < r
        #pragma unroll
        for (int j = 0; j < 4; ++j) {
            while (nxt[j] < lim) {
                val[j] = __uint_as_float(pub[p[j]]);
                ++p[j];
                nxt[j] = (p[j] < e2[j]) ? ent[p[j]] : 0xFFFFFFFFu;
            }
        }
        f32x4 w; w.x = val[0]; w.y = val[1]; w.z = val[2]; w.w = val[3];
        __builtin_nontemporal_store(w, (f32x4*)(out + (size_t)r * NN + n0));
    }
}

// ---------- fallback path (proven R3, 2.26 ms): sequential scan ----------
__global__ void __launch_bounds__(1024) k_seq(const int* __restrict__ edges,
                                              const float* __restrict__ theta,
                                              float* __restrict__ X,
                                              float* __restrict__ out_kappa,
                                              float* __restrict__ md) {
    const int tid = threadIdx.x;
    const float eps = sigmoid_f(theta[0]);
    int u = edges[3 * tid + 0];
    int v = edges[3 * tid + 1];
    int s = edges[3 * tid + 2];
    for (int t = 0; t < NSTEP; ++t) {
        int nu = 0, nv = 0, ns = 0;
        if (t + 1 < NSTEP) {
            const int nb = (t + 1) * 3 * EE + 3 * tid;
            nu = edges[nb + 0]; nv = edges[nb + 1]; ns = edges[nb + 2];
        }
        float xu = __hip_atomic_load(&X[u], RLX, WGS);
        float xv = __hip_atomic_load(&X[v], RLX, WGS);
        float diff = xu - xv;
        out_kappa[t * EE + tid] = sigmoid_f(RHO * (eps - fabsf(diff)));
        bool act = (s && diff != 0.0f);
        float m = act ? MU * diff : 0.0f;
        md[t * EE + tid] = m;
        __syncthreads();
        if (act) {
            __hip_atomic_fetch_add(&X[u], -m, RLX, WGS);
            __hip_atomic_fetch_add(&X[v],  m, RLX, WGS);
        }
        __syncthreads();
        u = nu; v = nv; s = ns;
    }
}

__global__ void k_fill_md(float* __restrict__ out,
                          const int* __restrict__ off, const int* __restrict__ cur,
                          const unsigned* __restrict__ ent,
                          const float* __restrict__ md) {
    int n = blockIdx.x * blockDim.x + threadIdx.x;
    if (n >= NN) return;
    float val = out[n];
    int p = off[n];
    const int e2 = p + cur[n];
    unsigned nxt = (p < e2) ? ent[p] : 0xFFFFFFFFu;
    for (int r = 1; r < TT; ++r) {
        const unsigned lim = ((unsigned)r) << 11;
        while (nxt < lim) {
            float m = md[nxt >> 1];
            val += (nxt & 1u) ? m : -m;
            ++p;
            nxt = (p < e2) ? ent[p] : 0xFFFFFFFFu;
        }
        out[(size_t)r * NN + n] = val;
    }
}
// ---------------------------------------------------------------------------

extern "C" void kernel_launch(void* const* d_in, const int* in_sizes, int n_in,
                              void* d_out, int out_size, void* d_ws, size_t ws_size,
                              hipStream_t stream) {
    const float* logit = (const float*)d_in[0];
    const float* theta = (const float*)d_in[1];
    const int*   edges = (const int*)d_in[2];
    float* out = (float*)d_out;
    float* kap = out + (size_t)TT * NN;

    char* ws = (char*)d_ws;
    float*    X0f  = (float*)ws;    ws += sizeof(float) * NN;
    int*      cnt  = (int*)ws;      ws += sizeof(int) * NN;
    int*      off  = (int*)ws;      ws += sizeof(int) * NN;
    int*      cur  = (int*)ws;      ws += sizeof(int) * NN;
    int*      bsum = (int*)ws;      ws += sizeof(int) * 128;
    int*      done = (int*)ws;      ws += sizeof(int) * 4;
    unsigned* ent  = (unsigned*)ws; ws += sizeof(unsigned) * CAP;
    // main path uses pub (CAP u32); fallback uses md (NE f32). They overlap.
    unsigned* pub = (unsigned*)ws;
    float*    md  = (float*)ws;

    const size_t need_main = (size_t)(4 * NN + 132) * 4 + (size_t)CAP * 4 * 2;
    const bool main_path = ws_size >= need_main;

    k_init <<<(NE + 255) / 256, 256, 0, stream>>>(logit, X0f, out, cnt, cur,
                                                  pub, done);
    k_count<<<(NE + 255) / 256, 256, 0, stream>>>(edges, cnt);
    k_scanA<<<SCAN_NB, 256, 0, stream>>>(cnt, bsum);
    k_scanC<<<SCAN_NB, 256, 0, stream>>>(cnt, bsum, off);
    k_place<<<(NE + 255) / 256, 256, 0, stream>>>(edges, off, cur, ent);
    k_sort <<<(NN + 255) / 256, 256, 0, stream>>>(off, cur, ent);

    bool flow_ok = false;
    if (main_path) {
        const int* a_edges = edges; const float* a_theta = theta;
        const float* a_x0 = X0f; const int* a_off = off; const int* a_cur = cur;
        const unsigned* a_ent = ent; unsigned* a_pub = pub; float* a_kap = kap;
        int* a_done = done;
        void* args[] = { &a_edges, &a_theta, &a_x0, &a_off, &a_cur,
                         &a_ent, &a_pub, &a_kap, &a_done };
        // Preferred: all 2044 chunk-blocks co-resident, frontier-gated.
        hipError_t e = hipLaunchCooperativeKernel((const void*)k_flow,
                                                  dim3(FLOWG_FULL), dim3(256),
                                                  args, 0, stream);
        if (e != hipSuccess) {
            (void)hipGetLastError();
            // Proven config: 512 blocks, 4 chunks each (gating still valid).
            e = hipLaunchCooperativeKernel((const void*)k_flow,
                                           dim3(FLOWG_HALF), dim3(256),
                                           args, 0, stream);
        }
        if (e == hipSuccess) {
            flow_ok = true;
            k_fill_pub<<<dim3(FILL_BX, NRC), 256, 0, stream>>>(out, X0f, off,
                                                               cur, ent, pub);
        } else {
            (void)hipGetLastError();
        }
    }
    if (!flow_ok) {
        // Proven sequential path (R3): single-block scan + delta fill.
        k_seq<<<1, 1024, 0, stream>>>(edges, theta, X0f, kap, md);
        k_fill_md<<<(NN + 255) / 256, 256, 0, stream>>>(out, off, cur, ent, md);
    }
}

// Round 14
// 245.150 us; speedup vs baseline: 1.6872x; 1.6872x over previous
//
#include <hip/hip_runtime.h>
#include <math.h>

#define NN 100000
#define TT 512
#define EE 1024
#define NSTEP (TT - 1)              // 511
#define NE (NSTEP * EE)             // 523,264 edges
#define NCHUNK (NE / 256)           // 2044 chunks of 256 edges (chunk ⊂ one step)
#define FLOWG 512                   // strided rounds = natural ~128-step window
#define MU 0.05f
#define RHO 32.0f
#define CAP (NE * 2)                // 1,046,528 max list entries
#define NOTREADY 0xFFFFFFFFu        // X values finite positive: never this bit pattern
#define SCAN_BLK 1024
#define SCAN_NB ((NN + SCAN_BLK - 1) / SCAN_BLK)   // 98
#define RB 32                       // rows per fill tile
#define NRC (TT / RB)               // 16 row chunks
#define FILL_BX ((NN / 4 + 255) / 256)             // 98 blocks in node dim

#define AGT __HIP_MEMORY_SCOPE_AGENT
#define WGS __HIP_MEMORY_SCOPE_WORKGROUP
#define RLX __ATOMIC_RELAXED

typedef float f32x4 __attribute__((ext_vector_type(4)));

__device__ __forceinline__ float sigmoid_f(float x) {
    return 1.0f / (1.0f + expf(-x));
}

__device__ __forceinline__ unsigned try_val(const unsigned* pub, int p) {
    return __hip_atomic_load((unsigned*)&pub[p], RLX, AGT);
}
__device__ __forceinline__ void publish(unsigned* pub, int p, float v) {
    __hip_atomic_store(&pub[p], __float_as_uint(v), RLX, AGT);
}

__device__ __forceinline__ int lower_bound(const unsigned* __restrict__ a,
                                           int lo, int hi, unsigned key) {
    while (lo < hi) {
        int mid = (lo + hi) >> 1;
        if (a[mid] < key) lo = mid + 1; else hi = mid;
    }
    return lo;
}

// Phase 0: X0 = sigmoid(logit) + row 0 + zero cnt/cur (i < NN), and reset
// publication slots (i < NE). Launched over NE range.
__global__ void k_init(const float* __restrict__ logit, float* __restrict__ X0f,
                       float* __restrict__ out, int* __restrict__ cnt,
                       int* __restrict__ cur, unsigned* __restrict__ pub) {
    int i = blockIdx.x * blockDim.x + threadIdx.x;
    if (i < NE) {
        pub[2 * i]     = NOTREADY;
        pub[2 * i + 1] = NOTREADY;
        if (i < NN) {
            float x = sigmoid_f(logit[i]);
            X0f[i] = x;
            out[i] = x;          // row 0 of X output
            cnt[i] = 0;
            cur[i] = 0;
        }
    }
}

// Phase 0b: count per-node list entries (only s==1 edges modify state).
__global__ void k_count(const int* __restrict__ edges, int* __restrict__ cnt) {
    int i = blockIdx.x * blockDim.x + threadIdx.x;
    if (i < NE) {
        int s = edges[3 * i + 2];
        if (s) {
            atomicAdd(&cnt[edges[3 * i + 0]], 1);
            atomicAdd(&cnt[edges[3 * i + 1]], 1);
        }
    }
}

// Phase 0c-A: per-block (1024 elems, 256 thr x int4) reduce -> bsum[b].
__global__ void __launch_bounds__(256) k_scanA(const int* __restrict__ cnt,
                                               int* __restrict__ bsum) {
    __shared__ int sh[256];
    const int t = threadIdx.x;
    const int base = blockIdx.x * SCAN_BLK + t * 4;
    int s = 0;
    if (base + 3 < NN) {
        const int4 v = *(const int4*)(cnt + base);
        s = v.x + v.y + v.z + v.w;
    } else {
        for (int k = 0; k < 4; ++k) if (base + k < NN) s += cnt[base + k];
    }
    sh[t] = s;
    __syncthreads();
    for (int o = 128; o > 0; o >>= 1) {
        if (t < o) sh[t] += sh[t + o];
        __syncthreads();
    }
    if (t == 0) bsum[blockIdx.x] = sh[0];
}

// Phase 0c-C: per-block local exclusive scan + block offset (each block
// redundantly scans the 98 block sums in LDS -> no separate scanB launch).
__global__ void __launch_bounds__(256) k_scanC(const int* __restrict__ cnt,
                                               const int* __restrict__ bsum,
                                               int* __restrict__ off) {
    __shared__ int sh[256];
    __shared__ int sb[128];
    const int t = threadIdx.x;

    if (t < 128) sb[t] = (t < SCAN_NB) ? bsum[t] : 0;
    __syncthreads();
    for (int o = 1; o < 128; o <<= 1) {
        int x = (t < 128 && t >= o) ? sb[t - o] : 0;
        __syncthreads();
        if (t < 128) sb[t] += x;            // inclusive scan of block sums
        __syncthreads();
    }
    const int boff = (blockIdx.x == 0) ? 0 : sb[blockIdx.x - 1];

    const int base = blockIdx.x * SCAN_BLK + t * 4;
    int a0 = 0, a1 = 0, a2 = 0, a3 = 0;
    if (base + 3 < NN) {
        const int4 v = *(const int4*)(cnt + base);
        a0 = v.x; a1 = v.y; a2 = v.z; a3 = v.w;
    } else {
        if (base + 0 < NN) a0 = cnt[base + 0];
        if (base + 1 < NN) a1 = cnt[base + 1];
        if (base + 2 < NN) a2 = cnt[base + 2];
    }
    const int s = a0 + a1 + a2 + a3;
    sh[t] = s;
    __syncthreads();
    for (int o = 1; o < 256; o <<= 1) {
        int x = (t >= o) ? sh[t - o] : 0;
        __syncthreads();
        sh[t] += x;
        __syncthreads();
    }
    int ex = sh[t] - s + boff;
    if (base + 3 < NN) {
        int4 w; w.x = ex; w.y = ex + a0; w.z = ex + a0 + a1; w.w = ex + a0 + a1 + a2;
        *(int4*)(off + base) = w;
    } else {
        if (base + 0 < NN) off[base + 0] = ex;
        if (base + 1 < NN) off[base + 1] = ex + a0;
        if (base + 2 < NN) off[base + 2] = ex + a0 + a1;
    }
}

// Phase 0d: place packed keys (t*EE+e)<<1 | side into per-node unordered lists.
__global__ void k_place(const int* __restrict__ edges,
                        const int* __restrict__ off, int* __restrict__ cur,
                        unsigned* __restrict__ ent) {
    int i = blockIdx.x * blockDim.x + threadIdx.x;
    if (i < NE) {
        int s = edges[3 * i + 2];
        if (s) {
            int u = edges[3 * i + 0];
            int v = edges[3 * i + 1];
            unsigned key = ((unsigned)i) << 1;
            ent[off[u] + atomicAdd(&cur[u], 1)] = key;        // side 0: -md
            ent[off[v] + atomicAdd(&cur[v], 1)] = key | 1u;   // side 1: +md
        }
    }
}

// Phase 0e: sort each node's list (keys unique -> deterministic). c ~ 5 avg.
__global__ void k_sort(const int* __restrict__ off, const int* __restrict__ cur,
                       unsigned* __restrict__ ent) {
    int n = blockIdx.x * blockDim.x + threadIdx.x;
    if (n >= NN) return;
    int lo = off[n], c = cur[n];
    for (int k = 1; k < c; ++k) {
        unsigned key = ent[lo + k];
        int j = k;
        while (j > 0 && ent[lo + j - 1] > key) {
            ent[lo + j] = ent[lo + j - 1];
            --j;
        }
        ent[lo + j] = key;
    }
}

// Phase 1: dataflow evaluation — PROVEN R9/R10 CONFIG (248.9 us total).
// 512 blocks, strided chunks: blocks finish in ~step order and take the next
// chunk, forming a free self-clocking ~128-step window (R12 proved removing
// it causes a probe storm: 177 MB fetch; R13 proved explicit gating is
// worse). Flattened poll loop (publishers may be in THIS wave); publishes
// first, kappa off the chain; tight-then-backoff polling.
__global__ void __launch_bounds__(256, 2)
k_flow(const int* __restrict__ edges, const float* __restrict__ theta,
       const float* __restrict__ X0f, const int* __restrict__ off,
       const int* __restrict__ cur, const unsigned* __restrict__ ent,
       unsigned* __restrict__ pub, float* __restrict__ out_kappa) {
    const float eps = sigmoid_f(theta[0]);
    for (int c = blockIdx.x; c < NCHUNK; c += gridDim.x) {
        const int i = (c << 8) + threadIdx.x;
        const int t = i >> 10;                     // i / EE
        const int u = edges[3 * i + 0];
        const int v = edges[3 * i + 1];
        const int s = edges[3 * i + 2];

        const unsigned stepkey = ((unsigned)t) << 11;

        const int lu = off[u], hu = lu + cur[u];
        const int qu = lower_bound(ent, lu, hu, stepkey);
        const int lv = off[v], hv = lv + cur[v];
        const int qv = lower_bound(ent, lv, hv, stepkey);

        int mu_ = -1, mv_ = -1;
        if (s) {
            const unsigned ku = ((unsigned)i) << 1;
            mu_ = qu; while (ent[mu_] != ku) ++mu_;
            const unsigned kv = ku | 1u;
            mv_ = qv; while (ent[mv_] != kv) ++mv_;
        }

        bool have_xu = (qu == lu);
        bool have_xv = (qv == lv);
        float xu = have_xu ? X0f[u] : 0.0f;
        float xv = have_xv ? X0f[v] : 0.0f;
        bool m_rdy = false;
        bool pu_done = (s == 0);
        bool pv_done = (s == 0);
        float m = 0.0f, diff = 0.0f;
        int tries = 0;

        while (!(m_rdy && pu_done && pv_done)) {
            if (!have_xu) {
                unsigned w = try_val(pub, qu - 1);
                if (w != NOTREADY) { xu = __uint_as_float(w); have_xu = true; }
            }
            if (!have_xv) {
                unsigned w = try_val(pub, qv - 1);
                if (w != NOTREADY) { xv = __uint_as_float(w); have_xv = true; }
            }
            if (have_xu && have_xv && !m_rdy) {
                diff = xu - xv;
                m = MU * diff;
                m_rdy = true;
            }
            if (m_rdy && !pu_done) {
                if (mu_ == qu) { publish(pub, mu_, xu - m); pu_done = true; }
                else {
                    unsigned w = try_val(pub, mu_ - 1);
                    if (w != NOTREADY) {
                        publish(pub, mu_, __uint_as_float(w) - m);
                        pu_done = true;
                    }
                }
            }
            if (m_rdy && !pv_done) {
                if (mv_ == qv) { publish(pub, mv_, xv + m); pv_done = true; }
                else {
                    unsigned w = try_val(pub, mv_ - 1);
                    if (w != NOTREADY) {
                        publish(pub, mv_, __uint_as_float(w) + m);
                        pv_done = true;
                    }
                }
            }
            if (!(m_rdy && pu_done && pv_done)) {
                ++tries;
                if (tries > 24)     __builtin_amdgcn_s_sleep(4);
                else if (tries > 6) __builtin_amdgcn_s_sleep(2);
            }
        }
        __builtin_nontemporal_store(sigmoid_f(RHO * (eps - fabsf(diff))),
                                    &out_kappa[i]);
    }
}

// Phase 2: reconstruct X rows from published running values. Separate launch
// => kernel-boundary coherence => plain cached pub reads. Non-temporal
// float4 stores: out is a write-only 204 MB stream, keep it out of L2.
__global__ void __launch_bounds__(256) k_fill_pub(float* __restrict__ out,
                                                  const float* __restrict__ X0f,
                                                  const int* __restrict__ off,
                                                  const int* __restrict__ cur,
                                                  const unsigned* __restrict__ ent,
                                                  const unsigned* __restrict__ pub) {
    const int n0 = (blockIdx.x * 256 + threadIdx.x) * 4;
    if (n0 >= NN) return;                  // NN % 4 == 0: full float4 valid
    const int r0 = blockIdx.y * RB;
    const unsigned key0 = ((unsigned)r0) << 11;

    int   p[4], e2[4];
    unsigned nxt[4];
    float val[4];
    #pragma unroll
    for (int j = 0; j < 4; ++j) {
        const int n = n0 + j;
        const int lo = off[n];
        e2[j] = lo + cur[n];
        int q = lower_bound(ent, lo, e2[j], key0);
        val[j] = (q > lo) ? __uint_as_float(pub[q - 1]) : X0f[n];
        p[j] = q;
        nxt[j] = (q < e2[j]) ? ent[q] : 0xFFFFFFFFu;
    }

    const int rstart = (r0 == 0) ? 1 : r0;   // row 0 written by k_init
    for (int r = rstart; r < r0 + RB; ++r) {
        const unsigned lim = ((unsigned)r) << 11;   // keys with t < r
        #pragma unroll
        for (int j = 0; j < 4; ++j) {
            while (nxt[j] < lim) {
                val[j] = __uint_as_float(pub[p[j]]);
                ++p[j];
                nxt[j] = (p[j] < e2[j]) ? ent[p[j]] : 0xFFFFFFFFu;
            }
        }
        f32x4 w; w.x = val[0]; w.y = val[1]; w.z = val[2]; w.w = val[3];
        __builtin_nontemporal_store(w, (f32x4*)(out + (size_t)r * NN + n0));
    }
}

// ---------- fallback path (proven R3, 2.26 ms): sequential scan ----------
__global__ void __launch_bounds__(1024) k_seq(const int* __restrict__ edges,
                                              const float* __restrict__ theta,
                                              float* __restrict__ X,
                                              float* __restrict__ out_kappa,
                                              float* __restrict__ md) {
    const int tid = threadIdx.x;
    const float eps = sigmoid_f(theta[0]);
    int u = edges[3 * tid + 0];
    int v = edges[3 * tid + 1];
    int s = edges[3 * tid + 2];
    for (int t = 0; t < NSTEP; ++t) {
        int nu = 0, nv = 0, ns = 0;
        if (t + 1 < NSTEP) {
            const int nb = (t + 1) * 3 * EE + 3 * tid;
            nu = edges[nb + 0]; nv = edges[nb + 1]; ns = edges[nb + 2];
        }
        float xu = __hip_atomic_load(&X[u], RLX, WGS);
        float xv = __hip_atomic_load(&X[v], RLX, WGS);
        float diff = xu - xv;
        out_kappa[t * EE + tid] = sigmoid_f(RHO * (eps - fabsf(diff)));
        bool act = (s && diff != 0.0f);
        float m = act ? MU * diff : 0.0f;
        md[t * EE + tid] = m;
        __syncthreads();
        if (act) {
            __hip_atomic_fetch_add(&X[u], -m, RLX, WGS);
            __hip_atomic_fetch_add(&X[v],  m, RLX, WGS);
        }
        __syncthreads();
        u = nu; v = nv; s = ns;
    }
}

__global__ void k_fill_md(float* __restrict__ out,
                          const int* __restrict__ off, const int* __restrict__ cur,
                          const unsigned* __restrict__ ent,
                          const float* __restrict__ md) {
    int n = blockIdx.x * blockDim.x + threadIdx.x;
    if (n >= NN) return;
    float val = out[n];
    int p = off[n];
    const int e2 = p + cur[n];
    unsigned nxt = (p < e2) ? ent[p] : 0xFFFFFFFFu;
    for (int r = 1; r < TT; ++r) {
        const unsigned lim = ((unsigned)r) << 11;
        while (nxt < lim) {
            float m = md[nxt >> 1];
            val += (nxt & 1u) ? m : -m;
            ++p;
            nxt = (p < e2) ? ent[p] : 0xFFFFFFFFu;
        }
        out[(size_t)r * NN + n] = val;
    }
}
// ---------------------------------------------------------------------------

extern "C" void kernel_launch(void* const* d_in, const int* in_sizes, int n_in,
                              void* d_out, int out_size, void* d_ws, size_t ws_size,
                              hipStream_t stream) {
    const float* logit = (const float*)d_in[0];
    const float* theta = (const float*)d_in[1];
    const int*   edges = (const int*)d_in[2];
    float* out = (float*)d_out;
    float* kap = out + (size_t)TT * NN;

    char* ws = (char*)d_ws;
    float*    X0f  = (float*)ws;    ws += sizeof(float) * NN;
    int*      cnt  = (int*)ws;      ws += sizeof(int) * NN;
    int*      off  = (int*)ws;      ws += sizeof(int) * NN;
    int*      cur  = (int*)ws;      ws += sizeof(int) * NN;
    int*      bsum = (int*)ws;      ws += sizeof(int) * 128;
    unsigned* ent  = (unsigned*)ws; ws += sizeof(unsigned) * CAP;
    // main path uses pub (CAP u32); fallback uses md (NE f32). They overlap.
    unsigned* pub = (unsigned*)ws;
    float*    md  = (float*)ws;

    const size_t need_main = (size_t)(4 * NN + 128) * 4 + (size_t)CAP * 4 * 2;
    const bool main_path = ws_size >= need_main;

    k_init <<<(NE + 255) / 256, 256, 0, stream>>>(logit, X0f, out, cnt, cur, pub);
    k_count<<<(NE + 255) / 256, 256, 0, stream>>>(edges, cnt);
    k_scanA<<<SCAN_NB, 256, 0, stream>>>(cnt, bsum);
    k_scanC<<<SCAN_NB, 256, 0, stream>>>(cnt, bsum, off);
    k_place<<<(NE + 255) / 256, 256, 0, stream>>>(edges, off, cur, ent);
    k_sort <<<(NN + 255) / 256, 256, 0, stream>>>(off, cur, ent);

    bool flow_ok = false;
    if (main_path) {
        const int* a_edges = edges; const float* a_theta = theta;
        const float* a_x0 = X0f; const int* a_off = off; const int* a_cur = cur;
        const unsigned* a_ent = ent; unsigned* a_pub = pub; float* a_kap = kap;
        void* args[] = { &a_edges, &a_theta, &a_x0, &a_off, &a_cur,
                         &a_ent, &a_pub, &a_kap };
        hipError_t e = hipLaunchCooperativeKernel((const void*)k_flow,
                                                  dim3(FLOWG), dim3(256),
                                                  args, 0, stream);
        if (e == hipSuccess) {
            flow_ok = true;
            k_fill_pub<<<dim3(FILL_BX, NRC), 256, 0, stream>>>(out, X0f, off,
                                                               cur, ent, pub);
        } else {
            (void)hipGetLastError();
        }
    }
    if (!flow_ok) {
        // Proven sequential path (R3): single-block scan + delta fill.
        k_seq<<<1, 1024, 0, stream>>>(edges, theta, X0f, kap, md);
        k_fill_md<<<(NN + 255) / 256, 256, 0, stream>>>(out, off, cur, ent, md);
    }
}

// Round 15
// 236.465 us; speedup vs baseline: 1.7491x; 1.0367x over previous
//
#include <hip/hip_runtime.h>
#include <math.h>

#define NN 100000
#define TT 512
#define EE 1024
#define NSTEP (TT - 1)              // 511
#define NE (NSTEP * EE)             // 523,264 edges
#define NCHUNK (NE / 256)           // 2044 chunks of 256 edges (chunk ⊂ one step)
#define FLOWG 512                   // strided rounds = natural ~128-step window
#define MU 0.05f
#define RHO 32.0f
#define CAP (NE * 2)                // 1,046,528 max list entries
#define NOTREADY 0xFFFFFFFFu        // X values finite positive: never this bit pattern
#define SCAN_BLK 1024
#define SCAN_NB ((NN + SCAN_BLK - 1) / SCAN_BLK)   // 98
#define RB 64                       // rows per fill tile (2x amortization vs R14)
#define NRC (TT / RB)               // 8 row chunks
#define FILL_BX ((NN / 4 + 255) / 256)             // 98 blocks in node dim

#define AGT __HIP_MEMORY_SCOPE_AGENT
#define WGS __HIP_MEMORY_SCOPE_WORKGROUP
#define RLX __ATOMIC_RELAXED

typedef float f32x4 __attribute__((ext_vector_type(4)));

__device__ __forceinline__ float sigmoid_f(float x) {
    return 1.0f / (1.0f + expf(-x));
}

__device__ __forceinline__ unsigned try_val(const unsigned* pub, int p) {
    return __hip_atomic_load((unsigned*)&pub[p], RLX, AGT);
}
__device__ __forceinline__ void publish(unsigned* pub, int p, float v) {
    __hip_atomic_store(&pub[p], __float_as_uint(v), RLX, AGT);
}

__device__ __forceinline__ int lower_bound(const unsigned* __restrict__ a,
                                           int lo, int hi, unsigned key) {
    while (lo < hi) {
        int mid = (lo + hi) >> 1;
        if (a[mid] < key) lo = mid + 1; else hi = mid;
    }
    return lo;
}

// Phase 0: X0 = sigmoid(logit) + row 0 + zero cnt/cur (i < NN), and reset
// publication slots (i < NE). Launched over NE range.
__global__ void k_init(const float* __restrict__ logit, float* __restrict__ X0f,
                       float* __restrict__ out, int* __restrict__ cnt,
                       int* __restrict__ cur, unsigned* __restrict__ pub) {
    int i = blockIdx.x * blockDim.x + threadIdx.x;
    if (i < NE) {
        pub[2 * i]     = NOTREADY;
        pub[2 * i + 1] = NOTREADY;
        if (i < NN) {
            float x = sigmoid_f(logit[i]);
            X0f[i] = x;
            out[i] = x;          // row 0 of X output
            cnt[i] = 0;
            cur[i] = 0;
        }
    }
}

// Phase 0b: count per-node list entries (only s==1 edges modify state).
__global__ void k_count(const int* __restrict__ edges, int* __restrict__ cnt) {
    int i = blockIdx.x * blockDim.x + threadIdx.x;
    if (i < NE) {
        int s = edges[3 * i + 2];
        if (s) {
            atomicAdd(&cnt[edges[3 * i + 0]], 1);
            atomicAdd(&cnt[edges[3 * i + 1]], 1);
        }
    }
}

// Phase 0c-A: per-block (1024 elems, 256 thr x int4) reduce -> bsum[b].
__global__ void __launch_bounds__(256) k_scanA(const int* __restrict__ cnt,
                                               int* __restrict__ bsum) {
    __shared__ int sh[256];
    const int t = threadIdx.x;
    const int base = blockIdx.x * SCAN_BLK + t * 4;
    int s = 0;
    if (base + 3 < NN) {
        const int4 v = *(const int4*)(cnt + base);
        s = v.x + v.y + v.z + v.w;
    } else {
        for (int k = 0; k < 4; ++k) if (base + k < NN) s += cnt[base + k];
    }
    sh[t] = s;
    __syncthreads();
    for (int o = 128; o > 0; o >>= 1) {
        if (t < o) sh[t] += sh[t + o];
        __syncthreads();
    }
    if (t == 0) bsum[blockIdx.x] = sh[0];
}

// Phase 0c-C: per-block local exclusive scan + block offset (each block
// redundantly scans the 98 block sums in LDS -> no separate scanB launch).
__global__ void __launch_bounds__(256) k_scanC(const int* __restrict__ cnt,
                                               const int* __restrict__ bsum,
                                               int* __restrict__ off) {
    __shared__ int sh[256];
    __shared__ int sb[128];
    const int t = threadIdx.x;

    if (t < 128) sb[t] = (t < SCAN_NB) ? bsum[t] : 0;
    __syncthreads();
    for (int o = 1; o < 128; o <<= 1) {
        int x = (t < 128 && t >= o) ? sb[t - o] : 0;
        __syncthreads();
        if (t < 128) sb[t] += x;            // inclusive scan of block sums
        __syncthreads();
    }
    const int boff = (blockIdx.x == 0) ? 0 : sb[blockIdx.x - 1];

    const int base = blockIdx.x * SCAN_BLK + t * 4;
    int a0 = 0, a1 = 0, a2 = 0, a3 = 0;
    if (base + 3 < NN) {
        const int4 v = *(const int4*)(cnt + base);
        a0 = v.x; a1 = v.y; a2 = v.z; a3 = v.w;
    } else {
        if (base + 0 < NN) a0 = cnt[base + 0];
        if (base + 1 < NN) a1 = cnt[base + 1];
        if (base + 2 < NN) a2 = cnt[base + 2];
    }
    const int s = a0 + a1 + a2 + a3;
    sh[t] = s;
    __syncthreads();
    for (int o = 1; o < 256; o <<= 1) {
        int x = (t >= o) ? sh[t - o] : 0;
        __syncthreads();
        sh[t] += x;
        __syncthreads();
    }
    int ex = sh[t] - s + boff;
    if (base + 3 < NN) {
        int4 w; w.x = ex; w.y = ex + a0; w.z = ex + a0 + a1; w.w = ex + a0 + a1 + a2;
        *(int4*)(off + base) = w;
    } else {
        if (base + 0 < NN) off[base + 0] = ex;
        if (base + 1 < NN) off[base + 1] = ex + a0;
        if (base + 2 < NN) off[base + 2] = ex + a0 + a1;
    }
}

// Phase 0d: place packed keys (t*EE+e)<<1 | side into per-node unordered lists.
__global__ void k_place(const int* __restrict__ edges,
                        const int* __restrict__ off, int* __restrict__ cur,
                        unsigned* __restrict__ ent) {
    int i = blockIdx.x * blockDim.x + threadIdx.x;
    if (i < NE) {
        int s = edges[3 * i + 2];
        if (s) {
            int u = edges[3 * i + 0];
            int v = edges[3 * i + 1];
            unsigned key = ((unsigned)i) << 1;
            ent[off[u] + atomicAdd(&cur[u], 1)] = key;        // side 0: -md
            ent[off[v] + atomicAdd(&cur[v], 1)] = key | 1u;   // side 1: +md
        }
    }
}

// Phase 0e: sort each node's list (keys unique -> deterministic). c ~ 5 avg.
__global__ void k_sort(const int* __restrict__ off, const int* __restrict__ cur,
                       unsigned* __restrict__ ent) {
    int n = blockIdx.x * blockDim.x + threadIdx.x;
    if (n >= NN) return;
    int lo = off[n], c = cur[n];
    for (int k = 1; k < c; ++k) {
        unsigned key = ent[lo + k];
        int j = k;
        while (j > 0 && ent[lo + j - 1] > key) {
            ent[lo + j] = ent[lo + j - 1];
            --j;
        }
        ent[lo + j] = key;
    }
}

// Phase 1: dataflow evaluation — proven R10/R14 config. 512 blocks, strided
// chunks (self-clocking ~128-step window; R12 proved full-parallel storms,
// R13 proved explicit gating is worse). Flattened poll loop (publishers may
// be in THIS wave); publishes first, kappa off the chain; tightened backoff
// (sleep 1/3): each sleep quantum sits directly on the critical chain.
__global__ void __launch_bounds__(256, 2)
k_flow(const int* __restrict__ edges, const float* __restrict__ theta,
       const float* __restrict__ X0f, const int* __restrict__ off,
       const int* __restrict__ cur, const unsigned* __restrict__ ent,
       unsigned* __restrict__ pub, float* __restrict__ out_kappa) {
    const float eps = sigmoid_f(theta[0]);
    for (int c = blockIdx.x; c < NCHUNK; c += gridDim.x) {
        const int i = (c << 8) + threadIdx.x;
        const int t = i >> 10;                     // i / EE
        const int u = edges[3 * i + 0];
        const int v = edges[3 * i + 1];
        const int s = edges[3 * i + 2];

        const unsigned stepkey = ((unsigned)t) << 11;

        const int lu = off[u], hu = lu + cur[u];
        const int qu = lower_bound(ent, lu, hu, stepkey);
        const int lv = off[v], hv = lv + cur[v];
        const int qv = lower_bound(ent, lv, hv, stepkey);

        int mu_ = -1, mv_ = -1;
        if (s) {
            const unsigned ku = ((unsigned)i) << 1;
            mu_ = qu; while (ent[mu_] != ku) ++mu_;
            const unsigned kv = ku | 1u;
            mv_ = qv; while (ent[mv_] != kv) ++mv_;
        }

        bool have_xu = (qu == lu);
        bool have_xv = (qv == lv);
        float xu = have_xu ? X0f[u] : 0.0f;
        float xv = have_xv ? X0f[v] : 0.0f;
        bool m_rdy = false;
        bool pu_done = (s == 0);
        bool pv_done = (s == 0);
        float m = 0.0f, diff = 0.0f;
        int tries = 0;

        while (!(m_rdy && pu_done && pv_done)) {
            if (!have_xu) {
                unsigned w = try_val(pub, qu - 1);
                if (w != NOTREADY) { xu = __uint_as_float(w); have_xu = true; }
            }
            if (!have_xv) {
                unsigned w = try_val(pub, qv - 1);
                if (w != NOTREADY) { xv = __uint_as_float(w); have_xv = true; }
            }
            if (have_xu && have_xv && !m_rdy) {
                diff = xu - xv;
                m = MU * diff;
                m_rdy = true;
            }
            if (m_rdy && !pu_done) {
                if (mu_ == qu) { publish(pub, mu_, xu - m); pu_done = true; }
                else {
                    unsigned w = try_val(pub, mu_ - 1);
                    if (w != NOTREADY) {
                        publish(pub, mu_, __uint_as_float(w) - m);
                        pu_done = true;
                    }
                }
            }
            if (m_rdy && !pv_done) {
                if (mv_ == qv) { publish(pub, mv_, xv + m); pv_done = true; }
                else {
                    unsigned w = try_val(pub, mv_ - 1);
                    if (w != NOTREADY) {
                        publish(pub, mv_, __uint_as_float(w) + m);
                        pv_done = true;
                    }
                }
            }
            if (!(m_rdy && pu_done && pv_done)) {
                ++tries;
                if (tries > 24)     __builtin_amdgcn_s_sleep(3);
                else if (tries > 6) __builtin_amdgcn_s_sleep(1);
            }
        }
        __builtin_nontemporal_store(sigmoid_f(RHO * (eps - fabsf(diff))),
                                    &out_kappa[i]);
    }
}

// Phase 2: reconstruct X rows from published running values. Separate launch
// => kernel-boundary coherence => plain cached pub reads. RB=64 rows/tile
// halves the per-tile init cost vs RB=32. NT float4 stores: out is a
// write-only 204 MB stream, keep it out of L2.
__global__ void __launch_bounds__(256) k_fill_pub(float* __restrict__ out,
                                                  const float* __restrict__ X0f,
                                                  const int* __restrict__ off,
                                                  const int* __restrict__ cur,
                                                  const unsigned* __restrict__ ent,
                                                  const unsigned* __restrict__ pub) {
    const int n0 = (blockIdx.x * 256 + threadIdx.x) * 4;
    if (n0 >= NN) return;                  // NN % 4 == 0: full float4 valid
    const int r0 = blockIdx.y * RB;
    const unsigned key0 = ((unsigned)r0) << 11;

    int   p[4], e2[4];
    unsigned nxt[4];
    float val[4];
    #pragma unroll
    for (int j = 0; j < 4; ++j) {
        const int n = n0 + j;
        const int lo = off[n];
        e2[j] = lo + cur[n];
        int q = lower_bound(ent, lo, e2[j], key0);
        val[j] = (q > lo) ? __uint_as_float(pub[q - 1]) : X0f[n];
        p[j] = q;
        nxt[j] = (q < e2[j]) ? ent[q] : 0xFFFFFFFFu;
    }

    const int rstart = (r0 == 0) ? 1 : r0;   // row 0 written by k_init
    for (int r = rstart; r < r0 + RB; ++r) {
        const unsigned lim = ((unsigned)r) << 11;   // keys with t < r
        #pragma unroll
        for (int j = 0; j < 4; ++j) {
            while (nxt[j] < lim) {
                val[j] = __uint_as_float(pub[p[j]]);
                ++p[j];
                nxt[j] = (p[j] < e2[j]) ? ent[p[j]] : 0xFFFFFFFFu;
            }
        }
        f32x4 w; w.x = val[0]; w.y = val[1]; w.z = val[2]; w.w = val[3];
        __builtin_nontemporal_store(w, (f32x4*)(out + (size_t)r * NN + n0));
    }
}

// ---------- fallback path (proven R3, 2.26 ms): sequential scan ----------
__global__ void __launch_bounds__(1024) k_seq(const int* __restrict__ edges,
                                              const float* __restrict__ theta,
                                              float* __restrict__ X,
                                              float* __restrict__ out_kappa,
                                              float* __restrict__ md) {
    const int tid = threadIdx.x;
    const float eps = sigmoid_f(theta[0]);
    int u = edges[3 * tid + 0];
    int v = edges[3 * tid + 1];
    int s = edges[3 * tid + 2];
    for (int t = 0; t < NSTEP; ++t) {
        int nu = 0, nv = 0, ns = 0;
        if (t + 1 < NSTEP) {
            const int nb = (t + 1) * 3 * EE + 3 * tid;
            nu = edges[nb + 0]; nv = edges[nb + 1]; ns = edges[nb + 2];
        }
        float xu = __hip_atomic_load(&X[u], RLX, WGS);
        float xv = __hip_atomic_load(&X[v], RLX, WGS);
        float diff = xu - xv;
        out_kappa[t * EE + tid] = sigmoid_f(RHO * (eps - fabsf(diff)));
        bool act = (s && diff != 0.0f);
        float m = act ? MU * diff : 0.0f;
        md[t * EE + tid] = m;
        __syncthreads();
        if (act) {
            __hip_atomic_fetch_add(&X[u], -m, RLX, WGS);
            __hip_atomic_fetch_add(&X[v],  m, RLX, WGS);
        }
        __syncthreads();
        u = nu; v = nv; s = ns;
    }
}

__global__ void k_fill_md(float* __restrict__ out,
                          const int* __restrict__ off, const int* __restrict__ cur,
                          const unsigned* __restrict__ ent,
                          const float* __restrict__ md) {
    int n = blockIdx.x * blockDim.x + threadIdx.x;
    if (n >= NN) return;
    float val = out[n];
    int p = off[n];
    const int e2 = p + cur[n];
    unsigned nxt = (p < e2) ? ent[p] : 0xFFFFFFFFu;
    for (int r = 1; r < TT; ++r) {
        const unsigned lim = ((unsigned)r) << 11;
        while (nxt < lim) {
            float m = md[nxt >> 1];
            val += (nxt & 1u) ? m : -m;
            ++p;
            nxt = (p < e2) ? ent[p] : 0xFFFFFFFFu;
        }
        out[(size_t)r * NN + n] = val;
    }
}
// ---------------------------------------------------------------------------

extern "C" void kernel_launch(void* const* d_in, const int* in_sizes, int n_in,
                              void* d_out, int out_size, void* d_ws, size_t ws_size,
                              hipStream_t stream) {
    const float* logit = (const float*)d_in[0];
    const float* theta = (const float*)d_in[1];
    const int*   edges = (const int*)d_in[2];
    float* out = (float*)d_out;
    float* kap = out + (size_t)TT * NN;

    char* ws = (char*)d_ws;
    float*    X0f  = (float*)ws;    ws += sizeof(float) * NN;
    int*      cnt  = (int*)ws;      ws += sizeof(int) * NN;
    int*      off  = (int*)ws;      ws += sizeof(int) * NN;
    int*      cur  = (int*)ws;      ws += sizeof(int) * NN;
    int*      bsum = (int*)ws;      ws += sizeof(int) * 128;
    unsigned* ent  = (unsigned*)ws; ws += sizeof(unsigned) * CAP;
    // main path uses pub (CAP u32); fallback uses md (NE f32). They overlap.
    unsigned* pub = (unsigned*)ws;
    float*    md  = (float*)ws;

    const size_t need_main = (size_t)(4 * NN + 128) * 4 + (size_t)CAP * 4 * 2;
    const bool main_path = ws_size >= need_main;

    k_init <<<(NE + 255) / 256, 256, 0, stream>>>(logit, X0f, out, cnt, cur, pub);
    k_count<<<(NE + 255) / 256, 256, 0, stream>>>(edges, cnt);
    k_scanA<<<SCAN_NB, 256, 0, stream>>>(cnt, bsum);
    k_scanC<<<SCAN_NB, 256, 0, stream>>>(cnt, bsum, off);
    k_place<<<(NE + 255) / 256, 256, 0, stream>>>(edges, off, cur, ent);
    k_sort <<<(NN + 255) / 256, 256, 0, stream>>>(off, cur, ent);

    bool flow_ok = false;
    if (main_path) {
        const int* a_edges = edges; const float* a_theta = theta;
        const float* a_x0 = X0f; const int* a_off = off; const int* a_cur = cur;
        const unsigned* a_ent = ent; unsigned* a_pub = pub; float* a_kap = kap;
        void* args[] = { &a_edges, &a_theta, &a_x0, &a_off, &a_cur,
                         &a_ent, &a_pub, &a_kap };
        hipError_t e = hipLaunchCooperativeKernel((const void*)k_flow,
                                                  dim3(FLOWG), dim3(256),
                                                  args, 0, stream);
        if (e == hipSuccess) {
            flow_ok = true;
            k_fill_pub<<<dim3(FILL_BX, NRC), 256, 0, stream>>>(out, X0f, off,
                                                               cur, ent, pub);
        } else {
            (void)hipGetLastError();
        }
    }
    if (!flow_ok) {
        // Proven sequential path (R3): single-block scan + delta fill.
        k_seq<<<1, 1024, 0, stream>>>(edges, theta, X0f, kap, md);
        k_fill_md<<<(NN + 255) / 256, 256, 0, stream>>>(out, off, cur, ent, md);
    }
}